// Round 2
// baseline (896.868 us; speedup 1.0000x reference)
//
#include <hip/hip_runtime.h>

#define D_MODEL 1024
#define SEQ 2048
#define BATCH 2
#define NH 16
#define DH 64
#define WIN 128
#define DFF 3072

typedef __bf16 bf16x8 __attribute__((ext_vector_type(8)));
typedef float f32x4 __attribute__((ext_vector_type(4)));
typedef unsigned short u16;

__device__ __forceinline__ float b2f(u16 u) {
    unsigned int x = ((unsigned int)u) << 16;
    return __uint_as_float(x);
}
__device__ __forceinline__ u16 f2b(float f) {
    unsigned int x = __float_as_uint(f);
    x += 0x7fffu + ((x >> 16) & 1u);
    return (u16)(x >> 16);
}

// ------------------------------------------------- transpose + f32->bf16 cvt
// out[c*R + r] = bf16(in[r*C + c]);  R, C multiples of 32.
__global__ __launch_bounds__(256) void transpose_cvt_k(
        const float* __restrict__ in, u16* __restrict__ out, int R, int C) {
    __shared__ u16 tile[32][33];
    int tx = threadIdx.x & 31;
    int ty = threadIdx.x >> 5;                 // 0..7
    int r0 = blockIdx.y * 32, c0 = blockIdx.x * 32;
#pragma unroll
    for (int i = 0; i < 4; ++i)
        tile[ty + i * 8][tx] = f2b(in[(size_t)(r0 + ty + i * 8) * C + c0 + tx]);
    __syncthreads();
#pragma unroll
    for (int i = 0; i < 4; ++i)
        out[(size_t)(c0 + ty + i * 8) * R + r0 + tx] = tile[tx][ty + i * 8];
}

// ---------------------------------------------------------------- layernorm
// One block (256 thr) per row of D_MODEL=1024. f32 in, bf16 out.
__global__ __launch_bounds__(256) void ln_k(
        const float* __restrict__ x, const float* __restrict__ g,
        const float* __restrict__ bta, u16* __restrict__ out) {
    int row = blockIdx.x;
    const float* xr = x + (size_t)row * D_MODEL;
    float v[4];
    float sum = 0.f, sq = 0.f;
#pragma unroll
    for (int i = 0; i < 4; ++i) {
        v[i] = xr[threadIdx.x + i * 256];
        sum += v[i];
        sq += v[i] * v[i];
    }
#pragma unroll
    for (int off = 32; off > 0; off >>= 1) {
        sum += __shfl_xor(sum, off, 64);
        sq  += __shfl_xor(sq, off, 64);
    }
    __shared__ float s1[4], s2[4];
    int w = threadIdx.x >> 6;
    if ((threadIdx.x & 63) == 0) { s1[w] = sum; s2[w] = sq; }
    __syncthreads();
    sum = s1[0] + s1[1] + s1[2] + s1[3];
    sq  = s2[0] + s2[1] + s2[2] + s2[3];
    float mu = sum * (1.f / D_MODEL);
    float var = sq * (1.f / D_MODEL) - mu * mu;
    float rstd = rsqrtf(var + 1e-5f);
    u16* outr = out + (size_t)row * D_MODEL;
#pragma unroll
    for (int i = 0; i < 4; ++i) {
        int c = threadIdx.x + i * 256;
        outr[c] = f2b((v[i] - mu) * rstd * g[c] + bta[c]);
    }
}

// ---------------------------------------------------------------- GEMM
// C[M,N] = A[M,K] @ Bt[N,K]^T + bias (+ GELU) (+ resid).  A,Bt bf16; bias,
// resid f32; C f32 or bf16 per OUTF32.  M%64==N%64==K%32==0.
// 256 threads = 4 waves; block tile 64x64, BK=32; wave w does rows w*16..+15.
// MFMA 16x16x32 bf16 layouts (guide §3, m89-verified):
//   A frag:  lane holds A[m=lane&15][k=(lane>>4)*8 + j], j=0..7 (contiguous)
//   B frag:  lane holds Bt[n=lane&15][k=(lane>>4)*8 + j]       (contiguous)
//   C/D:     col = lane&15, row = (lane>>4)*4 + reg
template <int GELU, int RESID, int OUTF32>
__global__ __launch_bounds__(256) void gemm_k(
        const u16* __restrict__ A, const u16* __restrict__ Bt,
        const float* __restrict__ bias, const float* __restrict__ resid,
        void* __restrict__ Cv, int M, int N, int K) {
    // rows padded to 40 bf16 = 80 B: keeps 16B alignment for b128 reads.
    __shared__ u16 As[64 * 40];
    __shared__ u16 Bs[64 * 40];
    int tid = threadIdx.x;
    int m0 = blockIdx.y * 64, n0 = blockIdx.x * 64;
    int r = tid >> 2, c8 = (tid & 3) * 8;      // staging: 16B per thread per tile
    const u16* gA = A + (size_t)(m0 + r) * K + c8;
    const u16* gB = Bt + (size_t)(n0 + r) * K + c8;

    f32x4 acc[4] = {{0.f, 0.f, 0.f, 0.f}, {0.f, 0.f, 0.f, 0.f},
                    {0.f, 0.f, 0.f, 0.f}, {0.f, 0.f, 0.f, 0.f}};
    int w = tid >> 6, lane = tid & 63;
    int qd = lane >> 4, l15 = lane & 15;

    for (int k0 = 0; k0 < K; k0 += 32) {
        __syncthreads();                       // protect LDS from prior reads
        *(uint4*)&As[r * 40 + c8] = *(const uint4*)(gA + k0);
        *(uint4*)&Bs[r * 40 + c8] = *(const uint4*)(gB + k0);
        __syncthreads();
        bf16x8 av = *(const bf16x8*)&As[(w * 16 + l15) * 40 + qd * 8];
#pragma unroll
        for (int nt = 0; nt < 4; ++nt) {
            bf16x8 bv = *(const bf16x8*)&Bs[(nt * 16 + l15) * 40 + qd * 8];
            acc[nt] = __builtin_amdgcn_mfma_f32_16x16x32_bf16(av, bv, acc[nt], 0, 0, 0);
        }
    }

#pragma unroll
    for (int nt = 0; nt < 4; ++nt) {
#pragma unroll
        for (int reg = 0; reg < 4; ++reg) {
            int row = m0 + w * 16 + qd * 4 + reg;
            int col = n0 + nt * 16 + l15;
            float val = acc[nt][reg] + bias[col];
            if (GELU) val = 0.5f * val * (1.f + erff(val * 0.70710678118654752f));
            if (RESID) val += resid[(size_t)row * N + col];
            if (OUTF32) ((float*)Cv)[(size_t)row * N + col] = val;
            else        ((u16*)Cv)[(size_t)row * N + col] = f2b(val);
        }
    }
}

// ---------------------------------------------------------------- attention
// One wave per (b, h, q); lane = dh index. Online softmax in fp32.
// qkv layout (bf16): [b, s, which*1024 + h*64 + d]
__global__ __launch_bounds__(256) void attn_k(
        const u16* __restrict__ qkv, u16* __restrict__ ctx) {
    int w = threadIdx.x >> 6, lane = threadIdx.x & 63;
    int s = blockIdx.x * 4 + w;
    int h = blockIdx.y, b = blockIdx.z;
    size_t qoff = ((size_t)(b * SEQ + s)) * (3 * D_MODEL) + h * DH + lane;
    float q = b2f(qkv[qoff]) * 0.125f;         // fold 1/sqrt(64)
    float m = -INFINITY, l = 0.f, acc = 0.f;
    int j0 = s - (WIN - 1);
    if (j0 < 0) j0 = 0;
    for (int j = j0; j <= s; ++j) {
        size_t rb = ((size_t)(b * SEQ + j)) * (3 * D_MODEL) + h * DH + lane;
        float kd = b2f(qkv[rb + D_MODEL]);
        float p = q * kd;
#pragma unroll
        for (int off = 32; off > 0; off >>= 1) p += __shfl_xor(p, off, 64);
        float mn = fmaxf(m, p);
        float al = __expf(m - mn);             // first iter: exp(-inf)=0
        float pe = __expf(p - mn);
        l = l * al + pe;
        float vd = b2f(qkv[rb + 2 * D_MODEL]);
        acc = acc * al + pe * vd;
        m = mn;
    }
    ctx[((size_t)(b * SEQ + s)) * D_MODEL + h * DH + lane] = f2b(acc / l);
}

// ---------------------------------------------------------------- launch
extern "C" void kernel_launch(void* const* d_in, const int* in_sizes, int n_in,
                              void* d_out, int out_size, void* d_ws, size_t ws_size,
                              hipStream_t stream) {
    (void)in_sizes; (void)n_in; (void)out_size; (void)ws_size;
    const float* x     = (const float*)d_in[0];
    const float* w_qkv = (const float*)d_in[1];
    const float* b_qkv = (const float*)d_in[2];
    const float* w_out = (const float*)d_in[3];
    const float* b_out = (const float*)d_in[4];
    const float* w_ff1 = (const float*)d_in[5];
    const float* b_ff1 = (const float*)d_in[6];
    const float* w_ff2 = (const float*)d_in[7];
    const float* b_ff2 = (const float*)d_in[8];
    const float* ln1g  = (const float*)d_in[9];
    const float* ln1b  = (const float*)d_in[10];
    const float* ln2g  = (const float*)d_in[11];
    const float* ln2b  = (const float*)d_in[12];
    float* out = (float*)d_out;

    const int M = BATCH * SEQ;                       // 4096
    char* base = (char*)d_ws;                        // 76 MiB total
    u16*   hbf   = (u16*)(base);                     //  8 MiB: LN out (reused)
    u16*   qkvbf = (u16*)(base + (8ll  << 20));      // 24 MiB: qkv / ff inter
    u16*   ctxbf = (u16*)(base + (32ll << 20));      //  8 MiB: attn out
    float* x2    = (float*)(base + (40ll << 20));    // 16 MiB: f32 residual
    u16*   wqkvT = (u16*)(base + (56ll << 20));      //  6 MiB
    u16*   woutT = (u16*)(base + (62ll << 20));      //  2 MiB
    u16*   wff1T = (u16*)(base + (64ll << 20));      //  6 MiB
    u16*   wff2T = (u16*)(base + (70ll << 20));      //  6 MiB

    // Pre-transpose weights to N-major (k-contiguous) bf16 for B fragments.
    transpose_cvt_k<<<dim3(3 * D_MODEL / 32, D_MODEL / 32), 256, 0, stream>>>(w_qkv, wqkvT, D_MODEL, 3 * D_MODEL);
    transpose_cvt_k<<<dim3(D_MODEL / 32, D_MODEL / 32), 256, 0, stream>>>(w_out, woutT, D_MODEL, D_MODEL);
    transpose_cvt_k<<<dim3(DFF / 32, D_MODEL / 32), 256, 0, stream>>>(w_ff1, wff1T, D_MODEL, DFF);
    transpose_cvt_k<<<dim3(D_MODEL / 32, DFF / 32), 256, 0, stream>>>(w_ff2, wff2T, DFF, D_MODEL);

    // hbf = bf16(LN1(x))
    ln_k<<<M, 256, 0, stream>>>(x, ln1g, ln1b, hbf);
    // qkvbf = bf16(hbf @ w_qkv + b_qkv)
    gemm_k<0, 0, 0><<<dim3(3 * D_MODEL / 64, M / 64), 256, 0, stream>>>(
        hbf, wqkvT, b_qkv, nullptr, qkvbf, M, 3 * D_MODEL, D_MODEL);
    // ctxbf = sliding-window attention(qkvbf)
    attn_k<<<dim3(SEQ / 4, NH, BATCH), 256, 0, stream>>>(qkvbf, ctxbf);
    // x2 = x + ctxbf @ w_out + b_out   (f32)
    gemm_k<0, 1, 1><<<dim3(D_MODEL / 64, M / 64), 256, 0, stream>>>(
        ctxbf, woutT, b_out, x, x2, M, D_MODEL, D_MODEL);
    // hbf = bf16(LN2(x2))
    ln_k<<<M, 256, 0, stream>>>(x2, ln2g, ln2b, hbf);
    // qkvbf = bf16(gelu(hbf @ w_ff1 + b_ff1))   (buffer reuse)
    gemm_k<1, 0, 0><<<dim3(DFF / 64, M / 64), 256, 0, stream>>>(
        hbf, wff1T, b_ff1, nullptr, qkvbf, M, DFF, D_MODEL);
    // out = x2 + qkvbf @ w_ff2 + b_ff2   (f32)
    gemm_k<0, 1, 1><<<dim3(D_MODEL / 64, M / 64), 256, 0, stream>>>(
        qkvbf, wff2T, b_ff2, x2, out, M, D_MODEL, DFF);
}

// Round 3
// 367.228 us; speedup vs baseline: 2.4423x; 2.4423x over previous
//
#include <hip/hip_runtime.h>

#define D_MODEL 1024
#define SEQ 2048
#define BATCH 2
#define NH 16
#define DH 64
#define WIN 128
#define DFF 3072

typedef __bf16 bf16x8 __attribute__((ext_vector_type(8)));
typedef float f32x4 __attribute__((ext_vector_type(4)));
typedef unsigned short u16;
typedef unsigned int u32;

__device__ __forceinline__ float b2f(u16 u) {
    unsigned int x = ((unsigned int)u) << 16;
    return __uint_as_float(x);
}
__device__ __forceinline__ u16 f2b(float f) {
    unsigned int x = __float_as_uint(f);
    x += 0x7fffu + ((x >> 16) & 1u);
    return (u16)(x >> 16);
}
__device__ __forceinline__ u32 pk2(float a, float b) {
    return (u32)f2b(a) | ((u32)f2b(b) << 16);
}

// ------------------------------------------------- transpose + f32->bf16 cvt
__global__ __launch_bounds__(256) void transpose_cvt_k(
        const float* __restrict__ in, u16* __restrict__ out, int R, int C) {
    __shared__ u16 tile[32][33];
    int tx = threadIdx.x & 31;
    int ty = threadIdx.x >> 5;
    int r0 = blockIdx.y * 32, c0 = blockIdx.x * 32;
#pragma unroll
    for (int i = 0; i < 4; ++i)
        tile[ty + i * 8][tx] = f2b(in[(size_t)(r0 + ty + i * 8) * C + c0 + tx]);
    __syncthreads();
#pragma unroll
    for (int i = 0; i < 4; ++i)
        out[(size_t)(c0 + ty + i * 8) * R + r0 + tx] = tile[tx][ty + i * 8];
}

// ---------------------------------------------------------------- layernorm
__global__ __launch_bounds__(256) void ln_k(
        const float* __restrict__ x, const float* __restrict__ g,
        const float* __restrict__ bta, u16* __restrict__ out) {
    int row = blockIdx.x;
    const float* xr = x + (size_t)row * D_MODEL;
    float v[4];
    float sum = 0.f, sq = 0.f;
#pragma unroll
    for (int i = 0; i < 4; ++i) {
        v[i] = xr[threadIdx.x + i * 256];
        sum += v[i];
        sq += v[i] * v[i];
    }
#pragma unroll
    for (int off = 32; off > 0; off >>= 1) {
        sum += __shfl_xor(sum, off, 64);
        sq  += __shfl_xor(sq, off, 64);
    }
    __shared__ float s1[4], s2[4];
    int w = threadIdx.x >> 6;
    if ((threadIdx.x & 63) == 0) { s1[w] = sum; s2[w] = sq; }
    __syncthreads();
    sum = s1[0] + s1[1] + s1[2] + s1[3];
    sq  = s2[0] + s2[1] + s2[2] + s2[3];
    float mu = sum * (1.f / D_MODEL);
    float var = sq * (1.f / D_MODEL) - mu * mu;
    float rstd = rsqrtf(var + 1e-5f);
    u16* outr = out + (size_t)row * D_MODEL;
#pragma unroll
    for (int i = 0; i < 4; ++i) {
        int c = threadIdx.x + i * 256;
        outr[c] = f2b((v[i] - mu) * rstd * g[c] + bta[c]);
    }
}

// ---------------------------------------------------------------- GEMM
// C[M,N] = A[M,K] @ Bt[N,K]^T + bias (+GELU) (+resid). 64x64 tile, 4 waves.
// VSPLIT (QKV gemm only): cols >= 2048 (the V block) are written TRANSPOSED
// to vt[bh][d][s] (s-contiguous) instead of C — feeds attention's PV mfma.
template <int GELU, int RESID, int OUTF32, int VSPLIT>
__global__ __launch_bounds__(256) void gemm_k(
        const u16* __restrict__ A, const u16* __restrict__ Bt,
        const float* __restrict__ bias, const float* __restrict__ resid,
        void* __restrict__ Cv, u16* __restrict__ vt, int M, int N, int K) {
    __shared__ u16 As[64 * 40];
    __shared__ u16 Bs[64 * 40];
    int tid = threadIdx.x;
    int m0 = blockIdx.y * 64, n0 = blockIdx.x * 64;
    int r = tid >> 2, c8 = (tid & 3) * 8;
    const u16* gA = A + (size_t)(m0 + r) * K + c8;
    const u16* gB = Bt + (size_t)(n0 + r) * K + c8;

    f32x4 acc[4] = {{0.f, 0.f, 0.f, 0.f}, {0.f, 0.f, 0.f, 0.f},
                    {0.f, 0.f, 0.f, 0.f}, {0.f, 0.f, 0.f, 0.f}};
    int w = tid >> 6, lane = tid & 63;
    int qd = lane >> 4, l15 = lane & 15;

    for (int k0 = 0; k0 < K; k0 += 32) {
        __syncthreads();
        *(uint4*)&As[r * 40 + c8] = *(const uint4*)(gA + k0);
        *(uint4*)&Bs[r * 40 + c8] = *(const uint4*)(gB + k0);
        __syncthreads();
        bf16x8 av = *(const bf16x8*)&As[(w * 16 + l15) * 40 + qd * 8];
#pragma unroll
        for (int nt = 0; nt < 4; ++nt) {
            bf16x8 bv = *(const bf16x8*)&Bs[(nt * 16 + l15) * 40 + qd * 8];
            acc[nt] = __builtin_amdgcn_mfma_f32_16x16x32_bf16(av, bv, acc[nt], 0, 0, 0);
        }
    }

    int row0 = m0 + w * 16 + qd * 4;
#pragma unroll
    for (int nt = 0; nt < 4; ++nt) {
        int col = n0 + nt * 16 + l15;
        float v[4];
#pragma unroll
        for (int reg = 0; reg < 4; ++reg) {
            v[reg] = acc[nt][reg] + bias[col];
            if (GELU) v[reg] = 0.5f * v[reg] * (1.f + erff(v[reg] * 0.70710678118654752f));
            if (RESID) v[reg] += resid[(size_t)(row0 + reg) * N + col];
        }
        if (VSPLIT && col >= 2 * D_MODEL) {
            // V block: write transposed bf16 to vt[bh][d][s], 4 consecutive s.
            int d = col - 2 * D_MODEL;
            int bh = (row0 >> 11) * NH + (d >> 6);
            ushort4 pkv = {f2b(v[0]), f2b(v[1]), f2b(v[2]), f2b(v[3])};
            *(ushort4*)&vt[((size_t)(bh * DH + (d & 63))) * SEQ + (row0 & (SEQ - 1))] = pkv;
        } else {
#pragma unroll
            for (int reg = 0; reg < 4; ++reg) {
                if (OUTF32) ((float*)Cv)[(size_t)(row0 + reg) * N + col] = v[reg];
                else        ((u16*)Cv)[(size_t)(row0 + reg) * N + col] = f2b(v[reg]);
            }
        }
    }
}

// ---------------------------------------------------------------- attention
// Flash-style, MFMA. One wave per 16-query tile; <=5 chunks of 32 keys.
// S^T = K @ Q^T via mfma(A=K, B=Q): C row=key=quad*4+reg, col=query=l15.
//   -> softmax reduce = local over 8 regs + shfl_xor(16,32) only.
// P (C-layout) -> PV operand layout via 8-shfl register butterfly.
// O^T = Vt @ P via mfma(A=Vt[dim][key], B=P): row=dim, col=query=l15,
//   so alpha/l rescale is a per-lane scalar.
__global__ __launch_bounds__(256) void attn_k(
        const u16* __restrict__ qkv, const u16* __restrict__ vt,
        u16* __restrict__ ctx) {
    int lane = threadIdx.x & 63, l15 = lane & 15, quad = lane >> 4;
    int t = blockIdx.x * 4 + (threadIdx.x >> 6);
    int qt = t & (SEQ / 16 - 1);
    int h  = (t >> 7) & (NH - 1);
    int b  = t >> 11;
    int q0 = qt * 16;
    int bh = b * NH + h;

    const u16* qrow = qkv + (size_t)(b * SEQ + q0 + l15) * (3 * D_MODEL) + h * DH + quad * 8;
    bf16x8 qf0 = *(const bf16x8*)(qrow);
    bf16x8 qf1 = *(const bf16x8*)(qrow + 32);
    const u16* kbase = qkv + (size_t)(b * SEQ) * (3 * D_MODEL) + D_MODEL + h * DH + quad * 8;
    const u16* vbase = vt + (size_t)(bh * DH) * SEQ;

    f32x4 o[4] = {{0.f, 0.f, 0.f, 0.f}, {0.f, 0.f, 0.f, 0.f},
                  {0.f, 0.f, 0.f, 0.f}, {0.f, 0.f, 0.f, 0.f}};
    float m = -1e30f, l = 0.f;
    int q = q0 + l15;
    int cs = q0 - (WIN - 1);
    cs = cs < 0 ? 0 : (cs & ~31);

    for (int c = cs; c <= q0 + 15; c += 32) {
        const u16* k0p = kbase + (size_t)(c + l15) * (3 * D_MODEL);
        const u16* k1p = k0p + (size_t)16 * (3 * D_MODEL);
        bf16x8 ka0 = *(const bf16x8*)(k0p);
        bf16x8 ka1 = *(const bf16x8*)(k0p + 32);
        bf16x8 kb0 = *(const bf16x8*)(k1p);
        bf16x8 kb1 = *(const bf16x8*)(k1p + 32);
        f32x4 s0 = {0.f, 0.f, 0.f, 0.f}, s1 = {0.f, 0.f, 0.f, 0.f};
        s0 = __builtin_amdgcn_mfma_f32_16x16x32_bf16(ka0, qf0, s0, 0, 0, 0);
        s0 = __builtin_amdgcn_mfma_f32_16x16x32_bf16(ka1, qf1, s0, 0, 0, 0);
        s1 = __builtin_amdgcn_mfma_f32_16x16x32_bf16(kb0, qf0, s1, 0, 0, 0);
        s1 = __builtin_amdgcn_mfma_f32_16x16x32_bf16(kb1, qf1, s1, 0, 0, 0);

        float p0[4], p1[4];
        float cm = -1e30f;
#pragma unroll
        for (int reg = 0; reg < 4; ++reg) {
            int k0i = c + quad * 4 + reg;
            p0[reg] = ((unsigned)(q - k0i) < WIN) ? s0[reg] * 0.125f : -1e30f;
            p1[reg] = ((unsigned)(q - k0i - 16) < WIN) ? s1[reg] * 0.125f : -1e30f;
            cm = fmaxf(cm, fmaxf(p0[reg], p1[reg]));
        }
        cm = fmaxf(cm, __shfl_xor(cm, 16, 64));
        cm = fmaxf(cm, __shfl_xor(cm, 32, 64));
        float mn = fmaxf(m, cm);
        float alpha = __expf(m - mn);
        m = mn;
        float ls = 0.f;
#pragma unroll
        for (int reg = 0; reg < 4; ++reg) {
            p0[reg] = __expf(p0[reg] - mn);
            p1[reg] = __expf(p1[reg] - mn);
            ls += p0[reg] + p1[reg];
        }
        ls += __shfl_xor(ls, 16, 64);
        ls += __shfl_xor(ls, 32, 64);
        l = l * alpha + ls;
#pragma unroll
        for (int mt = 0; mt < 4; ++mt) o[mt] *= alpha;

        // pack P rows into bf16 pairs; z = keys c+quad*4+{0..3}, w = +16.
        u32 z0 = pk2(p0[0], p0[1]), z1 = pk2(p0[2], p0[3]);
        u32 w0 = pk2(p1[0], p1[1]), w1 = pk2(p1[2], p1[3]);
        // butterfly: lane needs keys c + quad*8 + {0..7}
        int slo = ((quad & 1) * 2) * 16 + l15;
        int shi = slo + 16;
        u32 zl0 = (u32)__shfl((int)z0, slo, 64), zl1 = (u32)__shfl((int)z1, slo, 64);
        u32 zh0 = (u32)__shfl((int)z0, shi, 64), zh1 = (u32)__shfl((int)z1, shi, 64);
        u32 wl0 = (u32)__shfl((int)w0, slo, 64), wl1 = (u32)__shfl((int)w1, slo, 64);
        u32 wh0 = (u32)__shfl((int)w0, shi, 64), wh1 = (u32)__shfl((int)w1, shi, 64);
        alignas(16) u32 pr[4];
        pr[0] = quad < 2 ? zl0 : wl0;
        pr[1] = quad < 2 ? zl1 : wl1;
        pr[2] = quad < 2 ? zh0 : wh0;
        pr[3] = quad < 2 ? zh1 : wh1;
        bf16x8 pf = *(const bf16x8*)pr;

#pragma unroll
        for (int mt = 0; mt < 4; ++mt) {
            bf16x8 vf = *(const bf16x8*)(vbase + (size_t)(mt * 16 + l15) * SEQ + c + quad * 8);
            o[mt] = __builtin_amdgcn_mfma_f32_16x16x32_bf16(vf, pf, o[mt], 0, 0, 0);
        }
    }

    float rdiv = 1.f / l;
    u16* crow = ctx + (size_t)(b * SEQ + q0 + l15) * D_MODEL + h * DH;
#pragma unroll
    for (int mt = 0; mt < 4; ++mt) {
        ushort4 pkv = {f2b(o[mt][0] * rdiv), f2b(o[mt][1] * rdiv),
                       f2b(o[mt][2] * rdiv), f2b(o[mt][3] * rdiv)};
        *(ushort4*)(crow + mt * 16 + quad * 4) = pkv;
    }
}

// ---------------------------------------------------------------- launch
extern "C" void kernel_launch(void* const* d_in, const int* in_sizes, int n_in,
                              void* d_out, int out_size, void* d_ws, size_t ws_size,
                              hipStream_t stream) {
    (void)in_sizes; (void)n_in; (void)out_size; (void)ws_size;
    const float* x     = (const float*)d_in[0];
    const float* w_qkv = (const float*)d_in[1];
    const float* b_qkv = (const float*)d_in[2];
    const float* w_out = (const float*)d_in[3];
    const float* b_out = (const float*)d_in[4];
    const float* w_ff1 = (const float*)d_in[5];
    const float* b_ff1 = (const float*)d_in[6];
    const float* w_ff2 = (const float*)d_in[7];
    const float* b_ff2 = (const float*)d_in[8];
    const float* ln1g  = (const float*)d_in[9];
    const float* ln1b  = (const float*)d_in[10];
    const float* ln2g  = (const float*)d_in[11];
    const float* ln2b  = (const float*)d_in[12];
    float* out = (float*)d_out;

    const int M = BATCH * SEQ;                       // 4096
    char* base = (char*)d_ws;                        // <= 76 MiB (proven fits)
    u16*   hbf   = (u16*)(base);                     //  8 MiB: LN out
    u16*   qkvbf = (u16*)(base + (8ll  << 20));      // 24 MiB: qkv / ff inter
    u16*   ctxbf = (u16*)(base + (32ll << 20));      //  8 MiB: attn out
    float* x2    = (float*)(base + (40ll << 20));    // 16 MiB: f32 residual
    // Vt overlays the x2 region: Vt live = [qkv-gemm .. attn]; x2 live =
    // [out-proj ..] — temporally disjoint on the serialized stream.
    u16*   vtbuf = (u16*)(base + (40ll << 20));      //  8 MiB: V^T [bh][d][s]
    u16*   wqkvT = (u16*)(base + (56ll << 20));      //  6 MiB
    u16*   woutT = (u16*)(base + (62ll << 20));      //  2 MiB
    u16*   wff1T = (u16*)(base + (64ll << 20));      //  6 MiB
    u16*   wff2T = (u16*)(base + (70ll << 20));      //  6 MiB

    transpose_cvt_k<<<dim3(3 * D_MODEL / 32, D_MODEL / 32), 256, 0, stream>>>(w_qkv, wqkvT, D_MODEL, 3 * D_MODEL);
    transpose_cvt_k<<<dim3(D_MODEL / 32, D_MODEL / 32), 256, 0, stream>>>(w_out, woutT, D_MODEL, D_MODEL);
    transpose_cvt_k<<<dim3(DFF / 32, D_MODEL / 32), 256, 0, stream>>>(w_ff1, wff1T, D_MODEL, DFF);
    transpose_cvt_k<<<dim3(D_MODEL / 32, DFF / 32), 256, 0, stream>>>(w_ff2, wff2T, DFF, D_MODEL);

    ln_k<<<M, 256, 0, stream>>>(x, ln1g, ln1b, hbf);
    // qkv gemm: Q,K -> qkvbf; V -> vtbuf transposed
    gemm_k<0, 0, 0, 1><<<dim3(3 * D_MODEL / 64, M / 64), 256, 0, stream>>>(
        hbf, wqkvT, b_qkv, nullptr, qkvbf, vtbuf, M, 3 * D_MODEL, D_MODEL);
    attn_k<<<dim3(BATCH * NH * (SEQ / 16) / 4), 256, 0, stream>>>(qkvbf, vtbuf, ctxbf);
    gemm_k<0, 1, 1, 0><<<dim3(D_MODEL / 64, M / 64), 256, 0, stream>>>(
        ctxbf, woutT, b_out, x, x2, nullptr, M, D_MODEL, D_MODEL);
    ln_k<<<M, 256, 0, stream>>>(x2, ln2g, ln2b, hbf);
    gemm_k<1, 0, 0, 0><<<dim3(DFF / 64, M / 64), 256, 0, stream>>>(
        hbf, wff1T, b_ff1, nullptr, qkvbf, nullptr, M, DFF, D_MODEL);
    gemm_k<0, 1, 1, 0><<<dim3(D_MODEL / 64, M / 64), 256, 0, stream>>>(
        qkvbf, wff2T, b_ff2, x2, out, nullptr, M, D_MODEL, DFF);
}

// Round 4
// 344.005 us; speedup vs baseline: 2.6071x; 1.0675x over previous
//
#include <hip/hip_runtime.h>

#define D_MODEL 1024
#define SEQ 2048
#define BATCH 2
#define NH 16
#define DH 64
#define WIN 128
#define DFF 3072

typedef __bf16 bf16x8 __attribute__((ext_vector_type(8)));
typedef float f32x4 __attribute__((ext_vector_type(4)));
typedef unsigned short u16;
typedef unsigned int u32;

__device__ __forceinline__ float b2f(u16 u) {
    unsigned int x = ((unsigned int)u) << 16;
    return __uint_as_float(x);
}
__device__ __forceinline__ u16 f2b(float f) {
    unsigned int x = __float_as_uint(f);
    x += 0x7fffu + ((x >> 16) & 1u);
    return (u16)(x >> 16);
}
__device__ __forceinline__ u32 pk2(float a, float b) {
    return (u32)f2b(a) | ((u32)f2b(b) << 16);
}

// ------------------------------------------------- transpose + f32->bf16 cvt
__global__ __launch_bounds__(256) void transpose_cvt_k(
        const float* __restrict__ in, u16* __restrict__ out, int R, int C) {
    __shared__ u16 tile[32][33];
    int tx = threadIdx.x & 31;
    int ty = threadIdx.x >> 5;
    int r0 = blockIdx.y * 32, c0 = blockIdx.x * 32;
#pragma unroll
    for (int i = 0; i < 4; ++i)
        tile[ty + i * 8][tx] = f2b(in[(size_t)(r0 + ty + i * 8) * C + c0 + tx]);
    __syncthreads();
#pragma unroll
    for (int i = 0; i < 4; ++i)
        out[(size_t)(c0 + ty + i * 8) * R + r0 + tx] = tile[tx][ty + i * 8];
}

// ---------------------------------------------------------------- layernorm
__global__ __launch_bounds__(256) void ln_k(
        const float* __restrict__ x, const float* __restrict__ g,
        const float* __restrict__ bta, u16* __restrict__ out) {
    int row = blockIdx.x;
    const float* xr = x + (size_t)row * D_MODEL;
    float v[4];
    float sum = 0.f, sq = 0.f;
#pragma unroll
    for (int i = 0; i < 4; ++i) {
        v[i] = xr[threadIdx.x + i * 256];
        sum += v[i];
        sq += v[i] * v[i];
    }
#pragma unroll
    for (int off = 32; off > 0; off >>= 1) {
        sum += __shfl_xor(sum, off, 64);
        sq  += __shfl_xor(sq, off, 64);
    }
    __shared__ float s1[4], s2[4];
    int w = threadIdx.x >> 6;
    if ((threadIdx.x & 63) == 0) { s1[w] = sum; s2[w] = sq; }
    __syncthreads();
    sum = s1[0] + s1[1] + s1[2] + s1[3];
    sq  = s2[0] + s2[1] + s2[2] + s2[3];
    float mu = sum * (1.f / D_MODEL);
    float var = sq * (1.f / D_MODEL) - mu * mu;
    float rstd = rsqrtf(var + 1e-5f);
    u16* outr = out + (size_t)row * D_MODEL;
#pragma unroll
    for (int i = 0; i < 4; ++i) {
        int c = threadIdx.x + i * 256;
        outr[c] = f2b((v[i] - mu) * rstd * g[c] + bta[c]);
    }
}

// ---------------------------------------------------------------- GEMM
// m97-style: 128x128 block tile, 4 waves (2x2), 64x64 per wave, BK=32,
// global_load_lds width=16 staging, XOR-swizzled LDS to kill the 8-way
// ds_read_b128 conflict the DMA-forced unpadded layout would have.
// LDS element (row, c4*8..) stored at column (c4 ^ ((row>>1)&3))*8.
// VSPLIT (QKV gemm): cols >= 2048 (V block) written TRANSPOSED to
// vt[bh][d][s] for attention's PV mfma.
template <int GELU, int RESID, int OUTF32, int VSPLIT>
__global__ __launch_bounds__(256) void gemm_k(
        const u16* __restrict__ A, const u16* __restrict__ Bt,
        const float* __restrict__ bias, const float* __restrict__ resid,
        void* __restrict__ Cv, u16* __restrict__ vt, int M, int N, int K) {
    __shared__ u16 As[128 * 32];
    __shared__ u16 Bs[128 * 32];
    int tid = threadIdx.x;
    int w = tid >> 6, lane = tid & 63;
    int qd = lane >> 4, l15 = lane & 15;
    int m0 = blockIdx.y * 128, n0 = blockIdx.x * 128;

    // Staging: 16 chunks of 1024 B (64 lanes x 16 B); wave w owns chunks
    // w*4..w*4+3 (chunks 0-7 = A rows c*16.., 8-15 = B).
    const u16* gsrc[4];
    u16* ldst[4];
#pragma unroll
    for (int i = 0; i < 4; ++i) {
        int c = w * 4 + i;
        int cb = c & 7;
        int srow = cb * 16 + (lane >> 2);
        int scol = ((lane & 3) ^ ((srow >> 1) & 3)) * 8;   // XOR swizzle
        gsrc[i] = (c < 8 ? A + (size_t)(m0 + srow) * K
                         : Bt + (size_t)(n0 + srow) * K) + scol;
        ldst[i] = (c < 8 ? As : Bs) + cb * 512;            // + lane*8 elems by HW
    }

    int wm = w & 1, wn = w >> 1;
    f32x4 acc[4][4];
#pragma unroll
    for (int mt = 0; mt < 4; ++mt)
#pragma unroll
        for (int nt = 0; nt < 4; ++nt)
            acc[mt][nt] = (f32x4){0.f, 0.f, 0.f, 0.f};

    // Swizzled fragment read offsets (elements).
    int aoff[4], boff[4];
#pragma unroll
    for (int t = 0; t < 4; ++t) {
        int ar = wm * 64 + t * 16 + l15;
        aoff[t] = ar * 32 + ((qd ^ ((ar >> 1) & 3)) * 8);
        int br = wn * 64 + t * 16 + l15;
        boff[t] = br * 32 + ((qd ^ ((br >> 1) & 3)) * 8);
    }

    for (int k0 = 0; k0 < K; k0 += 32) {
        __syncthreads();                       // prior ds_reads done
#pragma unroll
        for (int i = 0; i < 4; ++i)
            __builtin_amdgcn_global_load_lds(
                (__attribute__((address_space(1))) void*)(gsrc[i] + k0),
                (__attribute__((address_space(3))) void*)(ldst[i]), 16, 0, 0);
        __syncthreads();                       // staging drained (vmcnt0)
        bf16x8 av[4], bv[4];
#pragma unroll
        for (int t = 0; t < 4; ++t) {
            av[t] = *(const bf16x8*)&As[aoff[t]];
            bv[t] = *(const bf16x8*)&Bs[boff[t]];
        }
#pragma unroll
        for (int mt = 0; mt < 4; ++mt)
#pragma unroll
            for (int nt = 0; nt < 4; ++nt)
                acc[mt][nt] = __builtin_amdgcn_mfma_f32_16x16x32_bf16(
                    av[mt], bv[nt], acc[mt][nt], 0, 0, 0);
    }

#pragma unroll
    for (int mt = 0; mt < 4; ++mt) {
        int row0 = m0 + wm * 64 + mt * 16 + qd * 4;
#pragma unroll
        for (int nt = 0; nt < 4; ++nt) {
            int col = n0 + wn * 64 + nt * 16 + l15;
            float v[4];
#pragma unroll
            for (int reg = 0; reg < 4; ++reg) {
                v[reg] = acc[mt][nt][reg] + bias[col];
                if (GELU) v[reg] = 0.5f * v[reg] * (1.f + erff(v[reg] * 0.70710678118654752f));
                if (RESID) v[reg] += resid[(size_t)(row0 + reg) * N + col];
            }
            if (VSPLIT && col >= 2 * D_MODEL) {
                int d = col - 2 * D_MODEL;
                int bh = (row0 >> 11) * NH + (d >> 6);
                ushort4 pkv = {f2b(v[0]), f2b(v[1]), f2b(v[2]), f2b(v[3])};
                *(ushort4*)&vt[((size_t)(bh * DH + (d & 63))) * SEQ + (row0 & (SEQ - 1))] = pkv;
            } else {
#pragma unroll
                for (int reg = 0; reg < 4; ++reg) {
                    if (OUTF32) ((float*)Cv)[(size_t)(row0 + reg) * N + col] = v[reg];
                    else        ((u16*)Cv)[(size_t)(row0 + reg) * N + col] = f2b(v[reg]);
                }
            }
        }
    }
}

// ---------------------------------------------------------------- attention
// Flash-style MFMA; one wave per 16-query tile; <=5 chunks of 32 keys.
__global__ __launch_bounds__(256) void attn_k(
        const u16* __restrict__ qkv, const u16* __restrict__ vt,
        u16* __restrict__ ctx) {
    int lane = threadIdx.x & 63, l15 = lane & 15, quad = lane >> 4;
    int t = blockIdx.x * 4 + (threadIdx.x >> 6);
    int qt = t & (SEQ / 16 - 1);
    int h  = (t >> 7) & (NH - 1);
    int b  = t >> 11;
    int q0 = qt * 16;
    int bh = b * NH + h;

    const u16* qrow = qkv + (size_t)(b * SEQ + q0 + l15) * (3 * D_MODEL) + h * DH + quad * 8;
    bf16x8 qf0 = *(const bf16x8*)(qrow);
    bf16x8 qf1 = *(const bf16x8*)(qrow + 32);
    const u16* kbase = qkv + (size_t)(b * SEQ) * (3 * D_MODEL) + D_MODEL + h * DH + quad * 8;
    const u16* vbase = vt + (size_t)(bh * DH) * SEQ;

    f32x4 o[4] = {{0.f, 0.f, 0.f, 0.f}, {0.f, 0.f, 0.f, 0.f},
                  {0.f, 0.f, 0.f, 0.f}, {0.f, 0.f, 0.f, 0.f}};
    float m = -1e30f, l = 0.f;
    int q = q0 + l15;
    int cs = q0 - (WIN - 1);
    cs = cs < 0 ? 0 : (cs & ~31);

    for (int c = cs; c <= q0 + 15; c += 32) {
        const u16* k0p = kbase + (size_t)(c + l15) * (3 * D_MODEL);
        const u16* k1p = k0p + (size_t)16 * (3 * D_MODEL);
        bf16x8 ka0 = *(const bf16x8*)(k0p);
        bf16x8 ka1 = *(const bf16x8*)(k0p + 32);
        bf16x8 kb0 = *(const bf16x8*)(k1p);
        bf16x8 kb1 = *(const bf16x8*)(k1p + 32);
        f32x4 s0 = {0.f, 0.f, 0.f, 0.f}, s1 = {0.f, 0.f, 0.f, 0.f};
        s0 = __builtin_amdgcn_mfma_f32_16x16x32_bf16(ka0, qf0, s0, 0, 0, 0);
        s0 = __builtin_amdgcn_mfma_f32_16x16x32_bf16(ka1, qf1, s0, 0, 0, 0);
        s1 = __builtin_amdgcn_mfma_f32_16x16x32_bf16(kb0, qf0, s1, 0, 0, 0);
        s1 = __builtin_amdgcn_mfma_f32_16x16x32_bf16(kb1, qf1, s1, 0, 0, 0);

        float p0[4], p1[4];
        float cm = -1e30f;
#pragma unroll
        for (int reg = 0; reg < 4; ++reg) {
            int k0i = c + quad * 4 + reg;
            p0[reg] = ((unsigned)(q - k0i) < WIN) ? s0[reg] * 0.125f : -1e30f;
            p1[reg] = ((unsigned)(q - k0i - 16) < WIN) ? s1[reg] * 0.125f : -1e30f;
            cm = fmaxf(cm, fmaxf(p0[reg], p1[reg]));
        }
        cm = fmaxf(cm, __shfl_xor(cm, 16, 64));
        cm = fmaxf(cm, __shfl_xor(cm, 32, 64));
        float mn = fmaxf(m, cm);
        float alpha = __expf(m - mn);
        m = mn;
        float ls = 0.f;
#pragma unroll
        for (int reg = 0; reg < 4; ++reg) {
            p0[reg] = __expf(p0[reg] - mn);
            p1[reg] = __expf(p1[reg] - mn);
            ls += p0[reg] + p1[reg];
        }
        ls += __shfl_xor(ls, 16, 64);
        ls += __shfl_xor(ls, 32, 64);
        l = l * alpha + ls;
#pragma unroll
        for (int mt = 0; mt < 4; ++mt) o[mt] *= alpha;

        u32 z0 = pk2(p0[0], p0[1]), z1 = pk2(p0[2], p0[3]);
        u32 w0 = pk2(p1[0], p1[1]), w1 = pk2(p1[2], p1[3]);
        int slo = ((quad & 1) * 2) * 16 + l15;
        int shi = slo + 16;
        u32 zl0 = (u32)__shfl((int)z0, slo, 64), zl1 = (u32)__shfl((int)z1, slo, 64);
        u32 zh0 = (u32)__shfl((int)z0, shi, 64), zh1 = (u32)__shfl((int)z1, shi, 64);
        u32 wl0 = (u32)__shfl((int)w0, slo, 64), wl1 = (u32)__shfl((int)w1, slo, 64);
        u32 wh0 = (u32)__shfl((int)w0, shi, 64), wh1 = (u32)__shfl((int)w1, shi, 64);
        alignas(16) u32 pr[4];
        pr[0] = quad < 2 ? zl0 : wl0;
        pr[1] = quad < 2 ? zl1 : wl1;
        pr[2] = quad < 2 ? zh0 : wh0;
        pr[3] = quad < 2 ? zh1 : wh1;
        bf16x8 pf = *(const bf16x8*)pr;

#pragma unroll
        for (int mt = 0; mt < 4; ++mt) {
            bf16x8 vf = *(const bf16x8*)(vbase + (size_t)(mt * 16 + l15) * SEQ + c + quad * 8);
            o[mt] = __builtin_amdgcn_mfma_f32_16x16x32_bf16(vf, pf, o[mt], 0, 0, 0);
        }
    }

    float rdiv = 1.f / l;
    u16* crow = ctx + (size_t)(b * SEQ + q0 + l15) * D_MODEL + h * DH;
#pragma unroll
    for (int mt = 0; mt < 4; ++mt) {
        ushort4 pkv = {f2b(o[mt][0] * rdiv), f2b(o[mt][1] * rdiv),
                       f2b(o[mt][2] * rdiv), f2b(o[mt][3] * rdiv)};
        *(ushort4*)(crow + mt * 16 + quad * 4) = pkv;
    }
}

// ---------------------------------------------------------------- launch
extern "C" void kernel_launch(void* const* d_in, const int* in_sizes, int n_in,
                              void* d_out, int out_size, void* d_ws, size_t ws_size,
                              hipStream_t stream) {
    (void)in_sizes; (void)n_in; (void)out_size; (void)ws_size;
    const float* x     = (const float*)d_in[0];
    const float* w_qkv = (const float*)d_in[1];
    const float* b_qkv = (const float*)d_in[2];
    const float* w_out = (const float*)d_in[3];
    const float* b_out = (const float*)d_in[4];
    const float* w_ff1 = (const float*)d_in[5];
    const float* b_ff1 = (const float*)d_in[6];
    const float* w_ff2 = (const float*)d_in[7];
    const float* b_ff2 = (const float*)d_in[8];
    const float* ln1g  = (const float*)d_in[9];
    const float* ln1b  = (const float*)d_in[10];
    const float* ln2g  = (const float*)d_in[11];
    const float* ln2b  = (const float*)d_in[12];
    float* out = (float*)d_out;

    const int M = BATCH * SEQ;                       // 4096
    char* base = (char*)d_ws;
    u16*   hbf   = (u16*)(base);                     //  8 MiB: LN out
    u16*   qkvbf = (u16*)(base + (8ll  << 20));      // 24 MiB: qkv / ff inter
    u16*   ctxbf = (u16*)(base + (32ll << 20));      //  8 MiB: attn out
    float* x2    = (float*)(base + (40ll << 20));    // 16 MiB: f32 residual
    u16*   vtbuf = (u16*)(base + (40ll << 20));      //  8 MiB: V^T (overlay, disjoint lifetime)
    u16*   wqkvT = (u16*)(base + (56ll << 20));      //  6 MiB
    u16*   woutT = (u16*)(base + (62ll << 20));      //  2 MiB
    u16*   wff1T = (u16*)(base + (64ll << 20));      //  6 MiB
    u16*   wff2T = (u16*)(base + (70ll << 20));      //  6 MiB

    transpose_cvt_k<<<dim3(3 * D_MODEL / 32, D_MODEL / 32), 256, 0, stream>>>(w_qkv, wqkvT, D_MODEL, 3 * D_MODEL);
    transpose_cvt_k<<<dim3(D_MODEL / 32, D_MODEL / 32), 256, 0, stream>>>(w_out, woutT, D_MODEL, D_MODEL);
    transpose_cvt_k<<<dim3(DFF / 32, D_MODEL / 32), 256, 0, stream>>>(w_ff1, wff1T, D_MODEL, DFF);
    transpose_cvt_k<<<dim3(D_MODEL / 32, DFF / 32), 256, 0, stream>>>(w_ff2, wff2T, DFF, D_MODEL);

    ln_k<<<M, 256, 0, stream>>>(x, ln1g, ln1b, hbf);
    gemm_k<0, 0, 0, 1><<<dim3(3 * D_MODEL / 128, M / 128), 256, 0, stream>>>(
        hbf, wqkvT, b_qkv, nullptr, qkvbf, vtbuf, M, 3 * D_MODEL, D_MODEL);
    attn_k<<<dim3(BATCH * NH * (SEQ / 16) / 4), 256, 0, stream>>>(qkvbf, vtbuf, ctxbf);
    gemm_k<0, 1, 1, 0><<<dim3(D_MODEL / 128, M / 128), 256, 0, stream>>>(
        ctxbf, woutT, b_out, x, x2, nullptr, M, D_MODEL, D_MODEL);
    ln_k<<<M, 256, 0, stream>>>(x2, ln2g, ln2b, hbf);
    gemm_k<1, 0, 0, 0><<<dim3(DFF / 128, M / 128), 256, 0, stream>>>(
        hbf, wff1T, b_ff1, nullptr, qkvbf, nullptr, M, DFF, D_MODEL);
    gemm_k<0, 1, 1, 0><<<dim3(D_MODEL / 128, M / 128), 256, 0, stream>>>(
        qkvbf, wff2T, b_ff2, x2, out, nullptr, M, D_MODEL, DFF);
}